// Round 1
// baseline (171.595 us; speedup 1.0000x reference)
//
#include <hip/hip_runtime.h>
#include <math.h>

// Problem constants (from reference setup_inputs)
#define BB 32
#define CC 512
#define HH 64
#define WW 64
#define RR 16
#define CR (CC / RR)   // 32

__device__ __forceinline__ float wave_sum64(float v) {
    #pragma unroll
    for (int off = 32; off > 0; off >>= 1)
        v += __shfl_xor(v, off, 64);
    return v;
}

// --- Kernel A: separable normalized Gaussian weights kx[b][64], ky[b][64] ---
// grid = B blocks, block = 64 threads (one wave)
__global__ void k_gauss(const float* __restrict__ mu,
                        const float* __restrict__ log_sigma,
                        float* __restrict__ kx, float* __restrict__ ky) {
    int b = blockIdx.x;
    int t = threadIdx.x;               // 0..63 -> grid position
    float sigma = expf(log_sigma[0]);
    float inv2s = 1.0f / (2.0f * sigma);
    float g = (float)t / 63.0f;        // linspace(0,1,64)
    float dh = g - mu[b * 2 + 0];      // grid_x varies along h, uses mu[:,0]
    float dw = g - mu[b * 2 + 1];      // grid_y varies along w, uses mu[:,1]
    float vx = expf(-dh * dh * inv2s);
    float vy = expf(-dw * dw * inv2s);
    float sx = wave_sum64(vx);
    float sy = wave_sum64(vy);
    // kernel[b,h,w] = (vx[h]/sx) * (vy[w]/sy)  is exactly the normalized 2D kernel
    kx[b * 64 + t] = vx / sx;
    ky[b * 64 + t] = vy / sy;
}

// --- Kernel B: squeezed[b][c] = sum_{h,w} x[b,c,h,w] * kx[b,h] * ky[b,w] ---
// grid = (C/4, B), block = 256 (4 waves); wave wv handles channel c = bx*4+wv
__global__ void k_squeeze(const float* __restrict__ x,
                          const float* __restrict__ kx,
                          const float* __restrict__ ky,
                          float* __restrict__ sq) {
    int b = blockIdx.y;
    int wv = threadIdx.x >> 6;
    int lane = threadIdx.x & 63;
    int c = blockIdx.x * 4 + wv;
    const float4* xp = (const float4*)(x + ((size_t)(b * CC + c)) * (HH * WW));
    int col = lane & 15;           // which float4 within a row (w0 = col*4)
    int hbase = lane >> 4;         // 0..3
    const float* kxb = kx + b * 64;
    const float* kyb = ky + b * 64;
    float a0 = 0.f, a1 = 0.f, a2 = 0.f, a3 = 0.f;
    #pragma unroll
    for (int it = 0; it < 16; ++it) {
        int h = hbase + it * 4;            // 64 lanes cover 4 full rows (1 KiB contiguous)
        float4 v = xp[h * 16 + col];
        float kh = kxb[h];
        a0 += v.x * kh; a1 += v.y * kh; a2 += v.z * kh; a3 += v.w * kh;
    }
    int w0 = col * 4;
    float partial = a0 * kyb[w0] + a1 * kyb[w0 + 1] + a2 * kyb[w0 + 2] + a3 * kyb[w0 + 3];
    float s = wave_sum64(partial);
    if (lane == 0) sq[b * CC + c] = s;
}

// --- Kernel C: weights[b][c] = sigmoid( relu(sq @ w1^T) @ w2^T ) ---
// grid = B blocks, block = 256
__global__ void k_mlp(const float* __restrict__ sq,
                      const float* __restrict__ w1,   // (CR, C)
                      const float* __restrict__ w2,   // (C, CR)
                      float* __restrict__ weights) {
    __shared__ float s_sq[CC];
    __shared__ float s_hid[CR];
    int b = blockIdx.x;
    int tid = threadIdx.x;
    for (int c = tid; c < CC; c += 256) s_sq[c] = sq[b * CC + c];
    __syncthreads();
    // hid[j]: 256 threads = 32 j-values x 8 segments of 64 columns
    int j = tid >> 3;
    int seg = tid & 7;
    float acc = 0.f;
    const float* w1r = w1 + j * CC + seg * 64;
    const float* sqr = s_sq + seg * 64;
    #pragma unroll 8
    for (int c = 0; c < 64; ++c) acc += sqr[c] * w1r[c];
    // reduce the 8 segment-partials (lanes j*8..j*8+7 are contiguous in a wave)
    acc += __shfl_xor(acc, 4, 64);
    acc += __shfl_xor(acc, 2, 64);
    acc += __shfl_xor(acc, 1, 64);
    if (seg == 0) s_hid[j] = fmaxf(acc, 0.0f);
    __syncthreads();
    for (int c = tid; c < CC; c += 256) {
        float a = 0.f;
        const float* w2r = w2 + c * CR;
        #pragma unroll
        for (int jj = 0; jj < CR; ++jj) a += s_hid[jj] * w2r[jj];
        weights[b * CC + c] = 1.0f / (1.0f + expf(-a));
    }
}

// --- Kernel D: out = x * weights[b,c], float4 grid-stride ---
__global__ void k_scale(const float* __restrict__ x,
                        const float* __restrict__ wt,
                        float* __restrict__ out, long n4) {
    long i = (long)blockIdx.x * blockDim.x + threadIdx.x;
    long stride = (long)gridDim.x * blockDim.x;
    for (; i < n4; i += stride) {
        float4 v = ((const float4*)x)[i];
        float s = wt[i >> 10];   // 1024 float4 per (b,c) channel
        float4 o;
        o.x = v.x * s; o.y = v.y * s; o.z = v.z * s; o.w = v.w * s;
        ((float4*)out)[i] = o;
    }
}

extern "C" void kernel_launch(void* const* d_in, const int* in_sizes, int n_in,
                              void* d_out, int out_size, void* d_ws, size_t ws_size,
                              hipStream_t stream) {
    const float* x  = (const float*)d_in[0];
    const float* mu = (const float*)d_in[1];
    const float* ls = (const float*)d_in[2];
    const float* w1 = (const float*)d_in[3];
    const float* w2 = (const float*)d_in[4];
    float* out = (float*)d_out;

    float* ws = (float*)d_ws;
    float* kx = ws;                       // B*64 = 2048 floats
    float* ky = ws + 2048;                // B*64 = 2048 floats
    float* sq = ws + 4096;                // B*C  = 16384 floats
    float* wt = ws + 4096 + 16384;        // B*C  = 16384 floats

    k_gauss<<<BB, 64, 0, stream>>>(mu, ls, kx, ky);
    k_squeeze<<<dim3(CC / 4, BB), 256, 0, stream>>>(x, kx, ky, sq);
    k_mlp<<<BB, 256, 0, stream>>>(sq, w1, w2, wt);
    k_scale<<<2048, 256, 0, stream>>>(x, wt, out, (long)BB * CC * HH * WW / 4);
}

// Round 3
// 133.414 us; speedup vs baseline: 1.2862x; 1.2862x over previous
//
#include <hip/hip_runtime.h>
#include <math.h>

// Problem constants (from reference setup_inputs)
#define BB 32
#define CC 512
#define HH 64
#define WW 64
#define RR 16
#define CR (CC / RR)   // 32

typedef float floatx4 __attribute__((ext_vector_type(4)));

__device__ __forceinline__ float wave_sum64(float v) {
    #pragma unroll
    for (int off = 32; off > 0; off >>= 1)
        v += __shfl_xor(v, off, 64);
    return v;
}

// --- Kernel B (fused gauss): squeezed[b][c] = sum_{h,w} x[b,c,h,w]*kx[b,h]*ky[b,w]
// grid = (C/4, B), block = 256 (4 waves); wave wv handles channel c = bx*4+wv.
// Forward sweep over x: leaves the TAIL of x resident in L3 for k_scale.
__global__ void k_squeeze(const float* __restrict__ x,
                          const float* __restrict__ mu,
                          const float* __restrict__ log_sigma,
                          float* __restrict__ sq) {
    __shared__ float s_kx[64];
    __shared__ float s_ky[64];
    int b = blockIdx.y;
    int tid = threadIdx.x;

    // Wave 0 computes the separable normalized Gaussian (redundant per block, trivial)
    if (tid < 64) {
        float sigma = expf(log_sigma[0]);
        float inv2s = 1.0f / (2.0f * sigma);
        float g = (float)tid / 63.0f;       // linspace(0,1,64)
        float dh = g - mu[b * 2 + 0];       // grid_x varies along h -> mu[:,0]
        float dw = g - mu[b * 2 + 1];       // grid_y varies along w -> mu[:,1]
        float vx = expf(-dh * dh * inv2s);
        float vy = expf(-dw * dw * inv2s);
        float sx = wave_sum64(vx);
        float sy = wave_sum64(vy);
        s_kx[tid] = vx / sx;
        s_ky[tid] = vy / sy;
    }
    __syncthreads();

    int wv = tid >> 6;
    int lane = tid & 63;
    int c = blockIdx.x * 4 + wv;
    const floatx4* xp = (const floatx4*)(x + ((size_t)(b * CC + c)) * (HH * WW));
    int col = lane & 15;           // which float4 within a row (w0 = col*4)
    int hbase = lane >> 4;         // 0..3
    float a0 = 0.f, a1 = 0.f, a2 = 0.f, a3 = 0.f;
    #pragma unroll
    for (int it = 0; it < 16; ++it) {
        int h = hbase + it * 4;            // 64 lanes cover 4 full rows (1 KiB contiguous)
        floatx4 v = xp[h * 16 + col];
        float kh = s_kx[h];
        a0 += v.x * kh; a1 += v.y * kh; a2 += v.z * kh; a3 += v.w * kh;
    }
    int w0 = col * 4;
    float partial = a0 * s_ky[w0] + a1 * s_ky[w0 + 1] + a2 * s_ky[w0 + 2] + a3 * s_ky[w0 + 3];
    float s = wave_sum64(partial);
    if (lane == 0) sq[b * CC + c] = s;
}

// --- Kernel C: weights[b][c] = sigmoid( relu(sq @ w1^T) @ w2^T ) ---
// grid = B blocks, block = 256
__global__ void k_mlp(const float* __restrict__ sq,
                      const float* __restrict__ w1,   // (CR, C)
                      const float* __restrict__ w2,   // (C, CR)
                      float* __restrict__ weights) {
    __shared__ float s_sq[CC];
    __shared__ float s_hid[CR];
    int b = blockIdx.x;
    int tid = threadIdx.x;
    for (int c = tid; c < CC; c += 256) s_sq[c] = sq[b * CC + c];
    __syncthreads();
    // hid[j]: 256 threads = 32 j-values x 8 segments of 64 columns
    int j = tid >> 3;
    int seg = tid & 7;
    float acc = 0.f;
    const float* w1r = w1 + j * CC + seg * 64;
    const float* sqr = s_sq + seg * 64;
    #pragma unroll 8
    for (int c = 0; c < 64; ++c) acc += sqr[c] * w1r[c];
    acc += __shfl_xor(acc, 4, 64);
    acc += __shfl_xor(acc, 2, 64);
    acc += __shfl_xor(acc, 1, 64);
    if (seg == 0) s_hid[j] = fmaxf(acc, 0.0f);
    __syncthreads();
    for (int c = tid; c < CC; c += 256) {
        float a = 0.f;
        const float* w2r = w2 + c * CR;
        #pragma unroll
        for (int jj = 0; jj < CR; ++jj) a += s_hid[jj] * w2r[jj];
        weights[b * CC + c] = 1.0f / (1.0f + expf(-a));
    }
}

// --- Kernel D: out = x * weights[b,c] ---
// REVERSE sweep: reads the tail of x first (hot in L3 from k_squeeze's forward
// sweep), ends at the head (hot for next replay's k_squeeze). Non-temporal
// stores keep the 268 MB output stream from evicting x out of L3.
__global__ void k_scale(const float* __restrict__ x,
                        const float* __restrict__ wt,
                        float* __restrict__ out, long n4) {
    long gid = (long)blockIdx.x * blockDim.x + threadIdx.x;
    long stride = (long)gridDim.x * blockDim.x;
    long niter = n4 / stride;                  // exact: 16777216 / 524288 = 32
    for (long j = niter; j-- > 0; ) {
        long i = j * stride + gid;
        floatx4 v = ((const floatx4*)x)[i];
        float s = wt[i >> 10];                 // 1024 float4 per (b,c) channel
        floatx4 o = v * s;
        __builtin_nontemporal_store(o, ((floatx4*)out) + i);
    }
}

extern "C" void kernel_launch(void* const* d_in, const int* in_sizes, int n_in,
                              void* d_out, int out_size, void* d_ws, size_t ws_size,
                              hipStream_t stream) {
    const float* x  = (const float*)d_in[0];
    const float* mu = (const float*)d_in[1];
    const float* ls = (const float*)d_in[2];
    const float* w1 = (const float*)d_in[3];
    const float* w2 = (const float*)d_in[4];
    float* out = (float*)d_out;

    float* ws = (float*)d_ws;
    float* sq = ws;                 // B*C = 16384 floats
    float* wt = ws + 16384;         // B*C = 16384 floats

    k_squeeze<<<dim3(CC / 4, BB), 256, 0, stream>>>(x, mu, ls, sq);
    k_mlp<<<BB, 256, 0, stream>>>(sq, w1, w2, wt);
    k_scale<<<2048, 256, 0, stream>>>(x, wt, out, (long)BB * CC * HH * WW / 4);
}